// Round 1
// baseline (47.562 us; speedup 1.0000x reference)
//
#include <hip/hip_runtime.h>

// Warp_Object bicubic warp: B=4, C=3, H=512, W=512, float32.
// out[k= b*C+c][y][x] = bicubic sample of img plane k at
//   (x + dx[(k%B)][y][x], y + dy[(k%B)][y][x])
// replicating the reference's tile-order quirk (displacement batch = k % B)
// and its exact normalize->denormalize arithmetic.

constexpr int B = 4, C = 3, H = 512, W = 512;
constexpr int HW = H * W;          // 2^18
constexpr int TOTAL = B * C * HW;  // 3,145,728

__global__ __launch_bounds__(256)
void warp_bicubic_kernel(const float* __restrict__ img,
                         const float* __restrict__ dx,
                         const float* __restrict__ dy,
                         float* __restrict__ out)
{
    int idx = blockIdx.x * blockDim.x + threadIdx.x;
    if (idx >= TOTAL) return;

    int k   = idx >> 18;          // b*C + c  (image plane)
    int pix = idx & (HW - 1);
    int y   = pix >> 9;
    int x   = pix & (W - 1);
    int bd  = k & (B - 1);        // displacement batch = (b*C+c) % B

    float dxv = dx[bd * HW + pix];
    float dyv = dy[bd * HW + pix];

    const float Wm1 = (float)(W - 1);
    const float Hm1 = (float)(H - 1);
    // exact reference arithmetic (normalize -> denormalize round trip)
    float newX = 2.0f * ((float)x + dxv) / Wm1 - 1.0f;
    float newY = 2.0f * ((float)y + dyv) / Hm1 - 1.0f;
    float xm = (newX + 1.0f) * Wm1 / 2.0f;
    float ym = (newY + 1.0f) * Hm1 / 2.0f;

    float x0f = floorf(xm), y0f = floorf(ym);
    float tx = xm - x0f, ty = ym - y0f;

    float tx2 = tx * tx, tx3 = tx2 * tx;
    float cx[4];
    cx[0] = (-tx3 + 2.0f * tx2 - tx) * 0.5f;
    cx[1] = (3.0f * tx3 - 5.0f * tx2 + 2.0f) * 0.5f;
    cx[2] = (-3.0f * tx3 + 4.0f * tx2 + tx) * 0.5f;
    cx[3] = 1.0f - (cx[0] + cx[1] + cx[2]);

    float ty2 = ty * ty, ty3 = ty2 * ty;
    float cyc[4];
    cyc[0] = (-ty3 + 2.0f * ty2 - ty) * 0.5f;
    cyc[1] = (3.0f * ty3 - 5.0f * ty2 + 2.0f) * 0.5f;
    cyc[2] = (-3.0f * ty3 + 4.0f * ty2 + ty) * 0.5f;
    cyc[3] = 1.0f - (cyc[0] + cyc[1] + cyc[2]);

    int x0 = (int)x0f, y0 = (int)y0f;
    int xi[4], yi[4];
#pragma unroll
    for (int o = 0; o < 4; ++o) {
        xi[o] = min(max(x0 + o - 1, 0), W - 1);
        yi[o] = min(max(y0 + o - 1, 0), H - 1);
    }

    const float* __restrict__ plane = img + (size_t)k * HW;
    float acc = 0.0f;
#pragma unroll
    for (int j = 0; j < 4; ++j) {
        const float* __restrict__ rowp = plane + yi[j] * W;
        float r = cx[0] * rowp[xi[0]] + cx[1] * rowp[xi[1]]
                + cx[2] * rowp[xi[2]] + cx[3] * rowp[xi[3]];
        acc += cyc[j] * r;
    }
    out[idx] = acc;
}

extern "C" void kernel_launch(void* const* d_in, const int* in_sizes, int n_in,
                              void* d_out, int out_size, void* d_ws, size_t ws_size,
                              hipStream_t stream) {
    const float* img = (const float*)d_in[0];
    const float* dx  = (const float*)d_in[1];
    const float* dy  = (const float*)d_in[2];
    float* out = (float*)d_out;

    dim3 block(256);
    dim3 grid(TOTAL / 256);
    hipLaunchKernelGGL(warp_bicubic_kernel, grid, block, 0, stream,
                       img, dx, dy, out);
}

// Round 2
// 26.489 us; speedup vs baseline: 1.7955x; 1.7955x over previous
//
#include <hip/hip_runtime.h>

// Warp_Object bicubic warp: B=4, C=3, H=512, W=512, float32.
// out[k=b*C+c][y][x] = bicubic sample of img plane k at
//   (x + dx[k%B][y][x], y + dy[k%B][y][x])
// Round 2: 2 px/thread, per-row unaligned dwordx4 gathers (4 loads/px instead
// of 16), branchless clamp handling via x-weight folding.

constexpr int B = 4, C = 3, H = 512, W = 512;
constexpr int HW = H * W;          // 2^18
constexpr int TOTAL = B * C * HW;  // 3,145,728
constexpr int PPT = 2;             // pixels per thread

typedef float f4 __attribute__((ext_vector_type(4)));
typedef f4 f4u __attribute__((aligned(4)));   // 4B-aligned float4 load

__global__ __launch_bounds__(256)
void warp_bicubic_kernel(const float* __restrict__ img,
                         const float* __restrict__ dxp,
                         const float* __restrict__ dyp,
                         float* __restrict__ out)
{
    int t = blockIdx.x * blockDim.x + threadIdx.x;
    int base = t * PPT;            // flat output index of first pixel
    int k    = base >> 18;         // image plane b*C + c
    int pix  = base & (HW - 1);
    int y    = pix >> 9;
    int bd   = k & (B - 1);        // displacement batch = k % B

    const float2 dx2 = *(const float2*)(dxp + bd * HW + pix);
    const float2 dy2 = *(const float2*)(dyp + bd * HW + pix);
    const float* __restrict__ plane = img + (size_t)k * HW;

    const float dxa[PPT] = {dx2.x, dx2.y};
    const float dya[PPT] = {dy2.x, dy2.y};

    f4    v[PPT][4];      // gathered rows
    float wx[PPT][4];     // x-weights (fold clamping into weights)
    float cy[PPT][4];     // y-coefficients

    const float Wm1 = (float)(W - 1);
    const float Hm1 = (float)(H - 1);

#pragma unroll
    for (int p = 0; p < PPT; ++p) {
        int x = (pix + p) & (W - 1);

        // exact reference arithmetic (normalize -> denormalize round trip)
        float newX = 2.0f * ((float)x + dxa[p]) / Wm1 - 1.0f;
        float newY = 2.0f * ((float)y + dya[p]) / Hm1 - 1.0f;
        float xm = (newX + 1.0f) * Wm1 * 0.5f;
        float ym = (newY + 1.0f) * Hm1 * 0.5f;

        float x0f = floorf(xm), y0f = floorf(ym);
        float tx = xm - x0f, ty = ym - y0f;

        float tx2 = tx * tx, tx3 = tx2 * tx;
        float cx0 = (-tx3 + 2.0f * tx2 - tx) * 0.5f;
        float cx1 = (3.0f * tx3 - 5.0f * tx2 + 2.0f) * 0.5f;
        float cx2 = (-3.0f * tx3 + 4.0f * tx2 + tx) * 0.5f;
        float cx3 = 1.0f - (cx0 + cx1 + cx2);

        float ty2 = ty * ty, ty3 = ty2 * ty;
        cy[p][0] = (-ty3 + 2.0f * ty2 - ty) * 0.5f;
        cy[p][1] = (3.0f * ty3 - 5.0f * ty2 + 2.0f) * 0.5f;
        cy[p][2] = (-3.0f * ty3 + 4.0f * ty2 + ty) * 0.5f;
        cy[p][3] = 1.0f - (cy[p][0] + cy[p][1] + cy[p][2]);

        int x0 = (int)x0f;
        int y0 = (int)y0f;
        int s  = min(max(x0 - 1, 0), W - 4);   // start of 4-wide load window

        // x-weights: interior -> plain cx; clamped -> fold duplicated taps
        if (x0 >= 1 && x0 <= W - 3) {
            wx[p][0] = cx0; wx[p][1] = cx1; wx[p][2] = cx2; wx[p][3] = cx3;
        } else {
            float w0 = 0.f, w1 = 0.f, w2 = 0.f, w3 = 0.f;
            const float cxa[4] = {cx0, cx1, cx2, cx3};
#pragma unroll
            for (int o = 0; o < 4; ++o) {
                int xi = min(max(x0 - 1 + o, 0), W - 1);
                int e  = xi - s;               // 0..3 always
                float c = cxa[o];
                w0 += (e == 0) ? c : 0.f;
                w1 += (e == 1) ? c : 0.f;
                w2 += (e == 2) ? c : 0.f;
                w3 += (e == 3) ? c : 0.f;
            }
            wx[p][0] = w0; wx[p][1] = w1; wx[p][2] = w2; wx[p][3] = w3;
        }

        // 4 row gathers, one unaligned dwordx4 each
#pragma unroll
        for (int j = 0; j < 4; ++j) {
            int yi = min(max(y0 - 1 + j, 0), H - 1);
            v[p][j] = *(const f4u*)(plane + yi * W + s);
        }
    }

    float res[PPT];
#pragma unroll
    for (int p = 0; p < PPT; ++p) {
        float acc = 0.0f;
#pragma unroll
        for (int j = 0; j < 4; ++j) {
            float r = v[p][j].x * wx[p][0] + v[p][j].y * wx[p][1]
                    + v[p][j].z * wx[p][2] + v[p][j].w * wx[p][3];
            acc += cy[p][j] * r;
        }
        res[p] = acc;
    }

    *(float2*)(out + base) = make_float2(res[0], res[1]);
}

extern "C" void kernel_launch(void* const* d_in, const int* in_sizes, int n_in,
                              void* d_out, int out_size, void* d_ws, size_t ws_size,
                              hipStream_t stream) {
    const float* img = (const float*)d_in[0];
    const float* dx  = (const float*)d_in[1];
    const float* dy  = (const float*)d_in[2];
    float* out = (float*)d_out;

    dim3 block(256);
    dim3 grid(TOTAL / (256 * PPT));
    hipLaunchKernelGGL(warp_bicubic_kernel, grid, block, 0, stream,
                       img, dx, dy, out);
}

// Round 4
// 25.570 us; speedup vs baseline: 1.8600x; 1.0359x over previous
//
#include <hip/hip_runtime.h>

// Warp_Object bicubic warp: B=4, C=3, H=512, W=512, float32.
// out[k=b*C+c][y][x] = bicubic sample of img plane k at displaced coords from
// (dx,dy)[k%B]. Quirk exploit: planes {bd, bd+4, bd+8} share displacement
// batch bd -> one thread computes all 3, amortizing coord math and dx/dy
// reads 3x. 2 px/thread, per-row unaligned dwordx4 gathers, nontemporal
// dx/dy loads and output stores (anti L2 pollution).

constexpr int B = 4, C = 3, H = 512, W = 512;
constexpr int HW = H * W;            // 2^18
constexpr int PPT = 2;               // pixels per thread
constexpr int NTHREADS = B * HW / PPT;   // 524288

typedef float f4 __attribute__((ext_vector_type(4)));
typedef f4 f4u __attribute__((aligned(4)));   // 4B-aligned float4 load
typedef float f2 __attribute__((ext_vector_type(2)));  // clang vector: NT-builtin ok

__global__ __launch_bounds__(256)
void warp_bicubic_kernel(const float* __restrict__ img,
                         const float* __restrict__ dxp,
                         const float* __restrict__ dyp,
                         float* __restrict__ out)
{
    int t    = blockIdx.x * blockDim.x + threadIdx.x;
    int base = t * PPT;                 // flat index within [B, H, W]
    int bd   = base >> 18;              // displacement batch
    int pix  = base & (HW - 1);
    int y    = pix >> 9;

    const f2 dx2 = __builtin_nontemporal_load((const f2*)(dxp + bd * HW + pix));
    const f2 dy2 = __builtin_nontemporal_load((const f2*)(dyp + bd * HW + pix));

    const float dxa[PPT] = {dx2.x, dx2.y};
    const float dya[PPT] = {dy2.x, dy2.y};

    float wx[PPT][4];     // x-weights (clamping folded in)
    float cy[PPT][4];     // y-coefficients
    int   roff[PPT][4];   // row gather offsets (plane-relative)

    const float Wm1 = (float)(W - 1);
    const float Hm1 = (float)(H - 1);

#pragma unroll
    for (int p = 0; p < PPT; ++p) {
        int x = (pix + p) & (W - 1);    // base even -> never wraps

        // exact reference arithmetic (normalize -> denormalize round trip)
        float newX = 2.0f * ((float)x + dxa[p]) / Wm1 - 1.0f;
        float newY = 2.0f * ((float)y + dya[p]) / Hm1 - 1.0f;
        float xm = (newX + 1.0f) * Wm1 * 0.5f;
        float ym = (newY + 1.0f) * Hm1 * 0.5f;

        float x0f = floorf(xm), y0f = floorf(ym);
        float tx = xm - x0f, ty = ym - y0f;

        float tx2 = tx * tx, tx3 = tx2 * tx;
        float cx0 = (-tx3 + 2.0f * tx2 - tx) * 0.5f;
        float cx1 = (3.0f * tx3 - 5.0f * tx2 + 2.0f) * 0.5f;
        float cx2 = (-3.0f * tx3 + 4.0f * tx2 + tx) * 0.5f;
        float cx3 = 1.0f - (cx0 + cx1 + cx2);

        float ty2 = ty * ty, ty3 = ty2 * ty;
        cy[p][0] = (-ty3 + 2.0f * ty2 - ty) * 0.5f;
        cy[p][1] = (3.0f * ty3 - 5.0f * ty2 + 2.0f) * 0.5f;
        cy[p][2] = (-3.0f * ty3 + 4.0f * ty2 + ty) * 0.5f;
        cy[p][3] = 1.0f - (cy[p][0] + cy[p][1] + cy[p][2]);

        int x0 = (int)x0f;
        int y0 = (int)y0f;
        int s  = min(max(x0 - 1, 0), W - 4);   // 4-wide load window start

        if (x0 >= 1 && x0 <= W - 3) {          // interior: weights = cx
            wx[p][0] = cx0; wx[p][1] = cx1; wx[p][2] = cx2; wx[p][3] = cx3;
        } else {                               // fold clamped taps into window
            float w0 = 0.f, w1 = 0.f, w2 = 0.f, w3 = 0.f;
            const float cxa[4] = {cx0, cx1, cx2, cx3};
#pragma unroll
            for (int o = 0; o < 4; ++o) {
                int xi = min(max(x0 - 1 + o, 0), W - 1);
                int e  = xi - s;               // 0..3 always
                float c = cxa[o];
                w0 += (e == 0) ? c : 0.f;
                w1 += (e == 1) ? c : 0.f;
                w2 += (e == 2) ? c : 0.f;
                w3 += (e == 3) ? c : 0.f;
            }
            wx[p][0] = w0; wx[p][1] = w1; wx[p][2] = w2; wx[p][3] = w3;
        }

#pragma unroll
        for (int j = 0; j < 4; ++j) {
            int yi = min(max(y0 - 1 + j, 0), H - 1);
            roff[p][j] = yi * W + s;
        }
    }

    // plane bases: k = bd + 4*c, c = 0..2  (all share this displacement)
    const float* __restrict__ pl0 = img + (size_t)(bd)     * HW;
    const float* __restrict__ pl1 = img + (size_t)(bd + 4) * HW;
    const float* __restrict__ pl2 = img + (size_t)(bd + 8) * HW;

    float acc[C][PPT] = {};
#pragma unroll
    for (int j = 0; j < 4; ++j) {
#pragma unroll
        for (int p = 0; p < PPT; ++p) {
            int ro = roff[p][j];
            f4 v0 = *(const f4u*)(pl0 + ro);
            f4 v1 = *(const f4u*)(pl1 + ro);
            f4 v2 = *(const f4u*)(pl2 + ro);
            float w0 = wx[p][0], w1 = wx[p][1], w2 = wx[p][2], w3 = wx[p][3];
            float cyj = cy[p][j];
            acc[0][p] += cyj * (v0.x * w0 + v0.y * w1 + v0.z * w2 + v0.w * w3);
            acc[1][p] += cyj * (v1.x * w0 + v1.y * w1 + v1.z * w2 + v1.w * w3);
            acc[2][p] += cyj * (v2.x * w0 + v2.y * w1 + v2.z * w2 + v2.w * w3);
        }
    }

#pragma unroll
    for (int c = 0; c < C; ++c) {
        f2 st; st.x = acc[c][0]; st.y = acc[c][1];
        __builtin_nontemporal_store(st, (f2*)(out + (size_t)(bd + 4 * c) * HW + pix));
    }
}

extern "C" void kernel_launch(void* const* d_in, const int* in_sizes, int n_in,
                              void* d_out, int out_size, void* d_ws, size_t ws_size,
                              hipStream_t stream) {
    const float* img = (const float*)d_in[0];
    const float* dx  = (const float*)d_in[1];
    const float* dy  = (const float*)d_in[2];
    float* out = (float*)d_out;

    dim3 block(256);
    dim3 grid(NTHREADS / 256);   // 2048 blocks
    hipLaunchKernelGGL(warp_bicubic_kernel, grid, block, 0, stream,
                       img, dx, dy, out);
}

// Round 5
// 23.287 us; speedup vs baseline: 2.0424x; 1.0980x over previous
//
#include <hip/hip_runtime.h>

// Warp_Object bicubic warp: B=4, C=3, H=512, W=512, float32.
// Round 5: latency-attack. 1 plane/thread, 2 px/thread, all 8 row-gathers
// issued before the coefficient VALU pipeline (MLP=8/thread), wave-uniform
// plane base via readfirstlane (1 VGPR addresses), launch_bounds(256,7)
// for ~7 waves/SIMD, XCD-chunked block swizzle, simplified xm=x+dx
// (drops 2 exact f32 divisions/px; <=3e-5 px rounding shift, harmless).

constexpr int B = 4, C = 3, H = 512, W = 512;
constexpr int HW = H * W;              // 2^18
constexpr int TOTAL = B * C * HW;      // 3,145,728
constexpr int PPT = 2;
constexpr int NTHREADS = TOTAL / PPT;  // 1,572,864
constexpr int NBLOCKS = NTHREADS / 256; // 6144 (divisible by 8)

typedef float f4 __attribute__((ext_vector_type(4)));
typedef f4 f4u __attribute__((aligned(4)));   // 4B-aligned float4 load
typedef float f2 __attribute__((ext_vector_type(2)));

__global__ __launch_bounds__(256, 7)
void warp_bicubic_kernel(const float* __restrict__ img,
                         const float* __restrict__ dxp,
                         const float* __restrict__ dyp,
                         float* __restrict__ out)
{
    // XCD-chunked swizzle: 8 XCDs x 768 contiguous blocks each
    int wg  = blockIdx.x;
    int swz = (wg & 7) * (NBLOCKS / 8) + (wg >> 3);
    int t   = swz * 256 + threadIdx.x;

    int base = t * PPT;
    int k    = base >> 18;            // plane b*C+c, wave-uniform
    int pix  = base & (HW - 1);
    int y    = pix >> 9;
    int x    = pix & (W - 1);         // even
    int bd   = k & (B - 1);           // displacement batch = k % B

    const f2 dx2 = *(const f2*)(dxp + bd * HW + pix);
    const f2 dy2 = *(const f2*)(dyp + bd * HW + pix);

    // wave-uniform plane base -> SGPR, gathers use 32-bit voffset
    int ks = __builtin_amdgcn_readfirstlane(k);
    const float* __restrict__ plane = img + (size_t)ks * HW;

    // ---- phase 1: minimal dep chain to addresses ----
    float tx[PPT], ty[PPT];
    int x0[PPT], y0[PPT], s[PPT];
    const float dxa[PPT] = {dx2.x, dx2.y};
    const float dya[PPT] = {dy2.x, dy2.y};
#pragma unroll
    for (int p = 0; p < PPT; ++p) {
        float xm = (float)(x + p) + dxa[p];   // == ref up to ~3e-5 px rounding
        float ym = (float)y + dya[p];
        float x0f = floorf(xm), y0f = floorf(ym);
        tx[p] = xm - x0f;
        ty[p] = ym - y0f;
        x0[p] = (int)x0f;
        y0[p] = (int)y0f;
        s[p]  = min(max(x0[p] - 1, 0), W - 4);
    }

    // ---- phase 2: issue all 8 row-gathers ----
    f4 v[PPT][4];
#pragma unroll
    for (int p = 0; p < PPT; ++p) {
#pragma unroll
        for (int j = 0; j < 4; ++j) {
            int yi = min(max(y0[p] - 1 + j, 0), H - 1);
            v[p][j] = *(const f4u*)(plane + yi * W + s[p]);
        }
    }

    // ---- phase 3: coefficient math (hides gather latency) ----
    float wx[PPT][4], cy[PPT][4];
#pragma unroll
    for (int p = 0; p < PPT; ++p) {
        float txv = tx[p], tyv = ty[p];
        float tx2 = txv * txv, tx3 = tx2 * txv;
        float cx0 = (-tx3 + 2.0f * tx2 - txv) * 0.5f;
        float cx1 = (3.0f * tx3 - 5.0f * tx2 + 2.0f) * 0.5f;
        float cx2 = (-3.0f * tx3 + 4.0f * tx2 + txv) * 0.5f;
        float cx3 = 1.0f - (cx0 + cx1 + cx2);

        float ty2 = tyv * tyv, ty3 = ty2 * tyv;
        cy[p][0] = (-ty3 + 2.0f * ty2 - tyv) * 0.5f;
        cy[p][1] = (3.0f * ty3 - 5.0f * ty2 + 2.0f) * 0.5f;
        cy[p][2] = (-3.0f * ty3 + 4.0f * ty2 + tyv) * 0.5f;
        cy[p][3] = 1.0f - (cy[p][0] + cy[p][1] + cy[p][2]);

        if (x0[p] >= 1 && x0[p] <= W - 3) {   // interior: weights = cx
            wx[p][0] = cx0; wx[p][1] = cx1; wx[p][2] = cx2; wx[p][3] = cx3;
        } else {                              // fold clamped taps into window
            float w0 = 0.f, w1 = 0.f, w2 = 0.f, w3 = 0.f;
            const float cxa[4] = {cx0, cx1, cx2, cx3};
#pragma unroll
            for (int o = 0; o < 4; ++o) {
                int xi = min(max(x0[p] - 1 + o, 0), W - 1);
                int e  = xi - s[p];           // 0..3 always
                float c = cxa[o];
                w0 += (e == 0) ? c : 0.f;
                w1 += (e == 1) ? c : 0.f;
                w2 += (e == 2) ? c : 0.f;
                w3 += (e == 3) ? c : 0.f;
            }
            wx[p][0] = w0; wx[p][1] = w1; wx[p][2] = w2; wx[p][3] = w3;
        }
    }

    // ---- phase 4: stencil reduce + store ----
    f2 st;
#pragma unroll
    for (int p = 0; p < PPT; ++p) {
        float acc = 0.0f;
#pragma unroll
        for (int j = 0; j < 4; ++j) {
            f4 vv = v[p][j];
            acc += cy[p][j] * (vv.x * wx[p][0] + vv.y * wx[p][1]
                             + vv.z * wx[p][2] + vv.w * wx[p][3]);
        }
        st[p] = acc;
    }
    __builtin_nontemporal_store(st, (f2*)(out + base));
}

extern "C" void kernel_launch(void* const* d_in, const int* in_sizes, int n_in,
                              void* d_out, int out_size, void* d_ws, size_t ws_size,
                              hipStream_t stream) {
    const float* img = (const float*)d_in[0];
    const float* dx  = (const float*)d_in[1];
    const float* dy  = (const float*)d_in[2];
    float* out = (float*)d_out;

    dim3 block(256);
    dim3 grid(NBLOCKS);
    hipLaunchKernelGGL(warp_bicubic_kernel, grid, block, 0, stream,
                       img, dx, dy, out);
}